// Round 1
// baseline (126.147 us; speedup 1.0000x reference)
//
#include <hip/hip_runtime.h>
#include <hip/hip_bf16.h>
#include <math.h>

// Problem constants (from reference)
#define NUM_TREES 256
#define DEPTH 6
#define TREE_DIM 2
#define INPUT_DIM 256
#define BATCH 2048
#define NLEAF 64            // 2^DEPTH
#define NCOLS (NUM_TREES * DEPTH)   // 1536

// ---------------------------------------------------------------------------
// Kernel A: sparsemax along axis 0 (INPUT_DIM) of feature_selection_logits
// [INPUT_DIM, NUM_TREES, DEPTH] -> selectors, same layout, into d_ws.
// One 256-thread block per (tree,depth) column. Bitonic sort (descending) in
// LDS, inclusive scan, support count, tau, projection.
// ---------------------------------------------------------------------------
__global__ __launch_bounds__(256) void sparsemax_kernel(
    const float* __restrict__ fsl,   // [256][1536]
    float* __restrict__ sel)         // [256][1536]
{
    __shared__ float s[256];
    __shared__ float cz[256];
    __shared__ int   red[256];

    const int col = blockIdx.x;      // 0..1535
    const int tid = threadIdx.x;     // 0..255

    const float x = fsl[tid * NCOLS + col];
    s[tid] = x;
    __syncthreads();

    // Bitonic sort, final order descending.
    for (int k = 2; k <= 256; k <<= 1) {
        for (int j = k >> 1; j > 0; j >>= 1) {
            const int ixj = tid ^ j;
            if (ixj > tid) {
                const float a = s[tid];
                const float b = s[ixj];
                const bool desc = ((tid & k) == 0);
                if (desc ? (a < b) : (a > b)) { s[tid] = b; s[ixj] = a; }
            }
            __syncthreads();
        }
    }

    // Inclusive prefix sum (Hillis-Steele, in place with barriers).
    cz[tid] = s[tid];
    __syncthreads();
    for (int off = 1; off < 256; off <<= 1) {
        const float add = (tid >= off) ? cz[tid - off] : 0.0f;
        __syncthreads();
        cz[tid] += add;
        __syncthreads();
    }

    // Support condition: 1 + k*z_k > cz_k  (k = tid+1)
    const float z = s[tid];
    const float c = cz[tid];
    const int   k1 = tid + 1;
    red[tid] = (1.0f + (float)k1 * z > c) ? k1 : 0;
    __syncthreads();
    for (int off = 128; off > 0; off >>= 1) {
        if (tid < off) red[tid] = max(red[tid], red[tid + off]);
        __syncthreads();
    }
    const int ksel = red[0];                       // >= 1 always
    const float tau = (cz[ksel - 1] - 1.0f) / (float)ksel;

    sel[tid * NCOLS + col] = fmaxf(x - tau, 0.0f);
}

// ---------------------------------------------------------------------------
// Kernel B: fused  fv = inputs @ selectors  ->  sparsemoid  ->  leaf-weight
// product DP  ->  response contraction.
// Tile: 128 batch rows x 8 trees per 256-thread block.
// Thread layout: tb = tid & 31 (batch sub-lane), tn = tid >> 5 (tree).
// Each thread owns 4 batch rows (tb, tb+32, tb+64, tb+96) x 1 tree x 6 depths.
// ---------------------------------------------------------------------------
#define TB_B 128
#define TB_N 8
#define TK   32

__global__ __launch_bounds__(256) void odt_fused_kernel(
    const float* __restrict__ inputs,   // [2048][256]
    const float* __restrict__ sel,      // [256][1536]
    const float* __restrict__ thr,      // [256][6]
    const float* __restrict__ logt,     // [256][6]
    const float* __restrict__ resp,     // [256][2][64]
    float* __restrict__ out)            // [2048][512]
{
    __shared__ float inA[TB_B][TK + 1];           // 128 x 33 (+1 pad: conflict-free col reads)
    __shared__ float selS[TK][TB_N * DEPTH + 1];  // 32 x 49
    __shared__ float respS[TB_N * TREE_DIM * NLEAF]; // 8 trees * 128 = 1024 floats

    const int tid = threadIdx.x;
    const int b0 = blockIdx.x * TB_B;
    const int n0 = blockIdx.y * TB_N;

    // Stage response tile once (1024 floats = 256 threads x float4).
    {
        const float4* rg = (const float4*)(resp + n0 * TREE_DIM * NLEAF);
        ((float4*)respS)[tid] = rg[tid];
    }

    const int tb = tid & 31;
    const int tn = tid >> 5;

    float acc[4][DEPTH];
#pragma unroll
    for (int p = 0; p < 4; ++p)
#pragma unroll
        for (int d = 0; d < DEPTH; ++d) acc[p][d] = 0.0f;

    for (int k0 = 0; k0 < INPUT_DIM; k0 += TK) {
        __syncthreads();
        // inputs chunk: 128 rows x 32 cols = 1024 float4 / 4 per thread
#pragma unroll
        for (int q = 0; q < 4; ++q) {
            const int l   = tid * 4 + q;   // 0..1023
            const int row = l >> 3;        // 0..127
            const int cv  = l & 7;         // float4 within row
            const float4 v = *(const float4*)(inputs + (b0 + row) * INPUT_DIM + k0 + cv * 4);
            inA[row][cv * 4 + 0] = v.x;
            inA[row][cv * 4 + 1] = v.y;
            inA[row][cv * 4 + 2] = v.z;
            inA[row][cv * 4 + 3] = v.w;
        }
        // selector chunk: 32 rows x 48 cols, 6 floats per thread
        {
            const int r  = tid >> 3;   // 0..31
            const int c8 = tid & 7;    // 0..7
            const float* g = sel + (k0 + r) * NCOLS + n0 * DEPTH + c8 * DEPTH;
#pragma unroll
            for (int q = 0; q < DEPTH; ++q) selS[r][c8 * DEPTH + q] = g[q];
        }
        __syncthreads();

#pragma unroll
        for (int kk = 0; kk < TK; ++kk) {
            float sv[DEPTH];
#pragma unroll
            for (int d = 0; d < DEPTH; ++d) sv[d] = selS[kk][tn * DEPTH + d];
#pragma unroll
            for (int p = 0; p < 4; ++p) {
                const float iv = inA[tb + 32 * p][kk];
#pragma unroll
                for (int d = 0; d < DEPTH; ++d)
                    acc[p][d] = fmaf(iv, sv[d], acc[p][d]);
            }
        }
    }

    // Epilogue: same tree for all 4 batch rows of this thread.
    const int n = n0 + tn;
    float th[DEPTH], et[DEPTH];
#pragma unroll
    for (int d = 0; d < DEPTH; ++d) {
        th[d] = thr[n * DEPTH + d];
        et[d] = expf(-logt[n * DEPTH + d]);
    }

#pragma unroll
    for (int p = 0; p < 4; ++p) {
        // sparsemoid(tl); bin factor for bit=0 is s, bit=1 is (1-s)
        float sd[DEPTH];
#pragma unroll
        for (int d = 0; d < DEPTH; ++d) {
            const float tl = (acc[p][d] - th[d]) * et[d];
            sd[d] = fminf(fmaxf(0.5f + 0.5f * tl, 0.0f), 1.0f);
        }
        // Leaf weights via doubling DP: 63 expansions, 126 mults.
        float w[NLEAF];
        w[0] = 1.0f;
        int sz = 1;
#pragma unroll
        for (int d = 0; d < DEPTH; ++d) {
#pragma unroll 32
            for (int c2 = 0; c2 < 32; ++c2) {
                if (c2 < sz) {
                    const float t = w[c2];
                    w[c2]      = t * sd[d];          // bit d == 0
                    w[c2 + sz] = t * (1.0f - sd[d]); // bit d == 1
                }
            }
            sz <<= 1;
        }
        // Contract with response (LDS broadcast across tb lanes).
        float o0 = 0.0f, o1 = 0.0f;
        const float* r0 = &respS[tn * TREE_DIM * NLEAF];
#pragma unroll
        for (int c2 = 0; c2 < NLEAF; ++c2) {
            o0 = fmaf(w[c2], r0[c2], o0);
            o1 = fmaf(w[c2], r0[NLEAF + c2], o1);
        }
        const int b = b0 + tb + 32 * p;
        out[b * (NUM_TREES * TREE_DIM) + n * TREE_DIM + 0] = o0;
        out[b * (NUM_TREES * TREE_DIM) + n * TREE_DIM + 1] = o1;
    }
}

// ---------------------------------------------------------------------------
extern "C" void kernel_launch(void* const* d_in, const int* in_sizes, int n_in,
                              void* d_out, int out_size, void* d_ws, size_t ws_size,
                              hipStream_t stream) {
    const float* inputs = (const float*)d_in[0];  // [2048][256]
    const float* fsl    = (const float*)d_in[1];  // [256][256][6]
    const float* thr    = (const float*)d_in[2];  // [256][6]
    const float* logt   = (const float*)d_in[3];  // [256][6]
    const float* resp   = (const float*)d_in[4];  // [256][2][64]
    float* out = (float*)d_out;                   // [2048][512]
    float* sel = (float*)d_ws;                    // selectors scratch: 1.5 MB

    hipLaunchKernelGGL(sparsemax_kernel, dim3(NCOLS), dim3(256), 0, stream, fsl, sel);
    hipLaunchKernelGGL(odt_fused_kernel, dim3(BATCH / TB_B, NUM_TREES / TB_N), dim3(256),
                       0, stream, inputs, sel, thr, logt, resp, out);
}

// Round 2
// 117.428 us; speedup vs baseline: 1.0742x; 1.0742x over previous
//
#include <hip/hip_runtime.h>
#include <hip/hip_bf16.h>
#include <math.h>

// Problem constants (from reference)
#define NUM_TREES 256
#define DEPTH 6
#define TREE_DIM 2
#define INPUT_DIM 256
#define BATCH 2048
#define NLEAF 64                    // 2^DEPTH
#define NCOLS (NUM_TREES * DEPTH)   // 1536
#define SELP_STRIDE (NUM_TREES * 8) // 2048: selectors padded to 8 per tree

// ---------------------------------------------------------------------------
// Kernel A: sparsemax along axis 0 via bisection on tau.
// One wave (64 lanes) per (tree,depth) column; each lane holds 4 of the 256
// values in registers. f(tau) = sum(max(x - tau, 0)) - 1 is monotone
// decreasing with a root in [max(x)-1, max(x)]; 32 halvings => tau exact to
// fp32 ulp. No LDS, no block barriers — replaces the 36-barrier bitonic sort.
// Output layout: selP[k][n*8 + d] (padded tree stride 8 for aligned float4
// staging in kernel B). Padding cols 6,7 are never read as operands.
// ---------------------------------------------------------------------------
__global__ __launch_bounds__(256) void sparsemax_bisect(
    const float* __restrict__ fsl,   // [256][1536]
    float* __restrict__ selP)        // [256][2048]
{
    const int lane = threadIdx.x & 63;
    const int wave = threadIdx.x >> 6;           // 0..3
    const int col  = blockIdx.x * 4 + wave;      // 0..1535
    const int n = col / 6;
    const int d = col - n * 6;

    float x[4];
#pragma unroll
    for (int j = 0; j < 4; ++j)
        x[j] = fsl[(j * 64 + lane) * NCOLS + col];

    // wave max
    float mx = fmaxf(fmaxf(x[0], x[1]), fmaxf(x[2], x[3]));
#pragma unroll
    for (int off = 32; off > 0; off >>= 1)
        mx = fmaxf(mx, __shfl_xor(mx, off));

    float lo = mx - 1.0f, hi = mx;
#pragma unroll 4
    for (int it = 0; it < 32; ++it) {
        const float mid = 0.5f * (lo + hi);
        float s = fmaxf(x[0] - mid, 0.0f) + fmaxf(x[1] - mid, 0.0f)
                + fmaxf(x[2] - mid, 0.0f) + fmaxf(x[3] - mid, 0.0f);
#pragma unroll
        for (int off = 32; off > 0; off >>= 1)
            s += __shfl_xor(s, off);
        if (s > 1.0f) lo = mid; else hi = mid;   // uniform across wave
    }
    const float tau = 0.5f * (lo + hi);

#pragma unroll
    for (int j = 0; j < 4; ++j)
        selP[(j * 64 + lane) * SELP_STRIDE + n * 8 + d] = fmaxf(x[j] - tau, 0.0f);
}

// ---------------------------------------------------------------------------
// Kernel B: fused  fv = inputs @ selectors -> sparsemoid -> leaf-weight DP
// -> response contraction.
// Tile: 64 batch rows x 8 trees, 128 threads, grid 32x32 = 1024 blocks.
// Thread (tb = tid&15, tn = tid>>4) owns rows 4*tb..4*tb+3 x tree tn.
// A-tile stored k-major (inAT[kk][row], pad->68 keeps 16B alignment) so the
// inner loop is one ds_read_b128 for 4 rows; selector reads are broadcast.
// ---------------------------------------------------------------------------
#define TB_B 64
#define TB_N 8
#define TK   32
#define APAD 68   // 64 + 4: multiple of 4 floats -> b128-aligned rows

__global__ __launch_bounds__(128) void odt_fused_kernel(
    const float* __restrict__ inputs,   // [2048][256]
    const float* __restrict__ selP,     // [256][2048]
    const float* __restrict__ thr,      // [256][6]
    const float* __restrict__ logt,     // [256][6]
    const float* __restrict__ resp,     // [256][2][64]
    float* __restrict__ out)            // [2048][512]
{
    __shared__ float inAT[TK][APAD];            // k-major A tile
    __shared__ float selS[TK][APAD];            // 8 trees * 8 cols (padded)
    __shared__ float respS[TB_N * TREE_DIM * NLEAF]; // 1024 floats

    const int tid = threadIdx.x;
    const int b0 = blockIdx.x * TB_B;
    const int n0 = blockIdx.y * TB_N;

    // Stage response tile once (1024 floats = 128 threads x 2 float4).
    {
        const float4* rg = (const float4*)(resp + n0 * TREE_DIM * NLEAF);
        ((float4*)respS)[tid]       = rg[tid];
        ((float4*)respS)[tid + 128] = rg[tid + 128];
    }

    const int tb = tid & 15;   // row group: rows 4*tb..4*tb+3
    const int tn = tid >> 4;   // tree 0..7

    float acc[4][DEPTH];
#pragma unroll
    for (int p = 0; p < 4; ++p)
#pragma unroll
        for (int d = 0; d < DEPTH; ++d) acc[p][d] = 0.0f;

    for (int k0 = 0; k0 < INPUT_DIM; k0 += TK) {
        __syncthreads();
        // A chunk: 64 rows x 32 cols, transposed into inAT[kk][row].
#pragma unroll
        for (int q = 0; q < 4; ++q) {
            const int idx = tid + 128 * q;     // 0..511
            const int row = idx >> 3;          // 0..63
            const int c4  = idx & 7;           // float4 within the 32-col chunk
            const float4 v = *(const float4*)(inputs + (b0 + row) * INPUT_DIM + k0 + c4 * 4);
            inAT[c4 * 4 + 0][row] = v.x;
            inAT[c4 * 4 + 1][row] = v.y;
            inAT[c4 * 4 + 2][row] = v.z;
            inAT[c4 * 4 + 3][row] = v.w;
        }
        // Selector chunk: 32 k-rows x 64 cols (8 trees x 8), aligned float4 copy.
#pragma unroll
        for (int q = 0; q < 4; ++q) {
            const int idx = tid + 128 * q;     // 0..511
            const int r   = idx >> 4;          // 0..31
            const int c4  = idx & 15;          // 0..15
            const float4 v = *(const float4*)(selP + (k0 + r) * SELP_STRIDE + n0 * 8 + c4 * 4);
            *(float4*)&selS[r][c4 * 4] = v;
        }
        __syncthreads();

#pragma unroll
        for (int kk = 0; kk < TK; ++kk) {
            const float4 iv = *(const float4*)&inAT[kk][4 * tb];
            const float4 s0 = *(const float4*)&selS[kk][tn * 8];
            const float2 s1 = *(const float2*)&selS[kk][tn * 8 + 4];
            const float ivp[4] = {iv.x, iv.y, iv.z, iv.w};
            const float sd[DEPTH] = {s0.x, s0.y, s0.z, s0.w, s1.x, s1.y};
#pragma unroll
            for (int p = 0; p < 4; ++p)
#pragma unroll
                for (int d = 0; d < DEPTH; ++d)
                    acc[p][d] = fmaf(ivp[p], sd[d], acc[p][d]);
        }
    }

    // Epilogue: tree n = n0 + tn, rows b0 + 4*tb + p.
    const int n = n0 + tn;
    float th[DEPTH], et[DEPTH];
#pragma unroll
    for (int d = 0; d < DEPTH; ++d) {
        th[d] = thr[n * DEPTH + d];
        et[d] = expf(-logt[n * DEPTH + d]);
    }

    const float* r0 = &respS[tn * TREE_DIM * NLEAF];
#pragma unroll
    for (int p = 0; p < 4; ++p) {
        float sd[DEPTH];
#pragma unroll
        for (int d = 0; d < DEPTH; ++d) {
            const float tl = (acc[p][d] - th[d]) * et[d];
            sd[d] = fminf(fmaxf(0.5f + 0.5f * tl, 0.0f), 1.0f);
        }
        // Leaf weights via doubling DP (bit d of leaf == 1 -> factor (1-s)).
        float w[NLEAF];
        w[0] = 1.0f;
#pragma unroll
        for (int d = 0; d < DEPTH; ++d) {
            const int sz = 1 << d;
#pragma unroll
            for (int c2 = 0; c2 < NLEAF / 2; ++c2) {
                if (c2 < sz) {
                    const float t = w[c2];
                    w[c2]      = t * sd[d];
                    w[c2 + sz] = t * (1.0f - sd[d]);
                }
            }
        }
        float o0 = 0.0f, o1 = 0.0f;
#pragma unroll
        for (int c2 = 0; c2 < NLEAF; ++c2) {
            o0 = fmaf(w[c2], r0[c2], o0);
            o1 = fmaf(w[c2], r0[NLEAF + c2], o1);
        }
        const int b = b0 + 4 * tb + p;
        float2 o = {o0, o1};
        *(float2*)(out + b * (NUM_TREES * TREE_DIM) + n * TREE_DIM) = o;
    }
}

// ---------------------------------------------------------------------------
extern "C" void kernel_launch(void* const* d_in, const int* in_sizes, int n_in,
                              void* d_out, int out_size, void* d_ws, size_t ws_size,
                              hipStream_t stream) {
    const float* inputs = (const float*)d_in[0];  // [2048][256]
    const float* fsl    = (const float*)d_in[1];  // [256][256][6]
    const float* thr    = (const float*)d_in[2];  // [256][6]
    const float* logt   = (const float*)d_in[3];  // [256][6]
    const float* resp   = (const float*)d_in[4];  // [256][2][64]
    float* out  = (float*)d_out;                  // [2048][512]
    float* selP = (float*)d_ws;                   // [256][2048] = 2 MB scratch

    hipLaunchKernelGGL(sparsemax_bisect, dim3(NCOLS / 4), dim3(256), 0, stream, fsl, selP);
    hipLaunchKernelGGL(odt_fused_kernel, dim3(BATCH / TB_B, NUM_TREES / TB_N), dim3(128),
                       0, stream, inputs, selP, thr, logt, resp, out);
}

// Round 3
// 91.077 us; speedup vs baseline: 1.3851x; 1.2893x over previous
//
#include <hip/hip_runtime.h>
#include <hip/hip_fp16.h>
#include <math.h>

// Problem constants (from reference)
#define NUM_TREES 256
#define DEPTH 6
#define TREE_DIM 2
#define INPUT_DIM 256
#define BATCH 2048
#define NLEAF 64                     // 2^DEPTH
#define NCOLS (NUM_TREES * DEPTH)    // 1536
#define KDIM INPUT_DIM

typedef _Float16 half8 __attribute__((ext_vector_type(8)));
typedef float floatx4 __attribute__((ext_vector_type(4)));

// ---------------------------------------------------------------------------
// Kernel A: sparsemax along axis 0 via bisection on tau (24 halvings: tau to
// ~6e-8, far below fp16 epilogue noise). One wave per (tree,depth) column.
// Output: selT[pc][k] fp16, COLUMN-major (k contiguous), pc = tree*8 + d
// (padded to 8 cols/tree). This makes kernel A's stores coalesced (128B/row)
// AND is exactly the MFMA B-fragment order (k-major per column), so kernel B
// stages B with zero transposition. Pad cols 6,7 are left as harness poison
// (0xAAAA as fp16 = -0.005, benign; MFMA columns are independent, epilogue
// never reads them).
// ---------------------------------------------------------------------------
__global__ __launch_bounds__(256) void sparsemax_bisect(
    const float* __restrict__ fsl,     // [256][1536] fp32
    _Float16* __restrict__ selT)       // [2048][256] fp16, col-major
{
    const int lane = threadIdx.x & 63;
    const int wave = threadIdx.x >> 6;           // 0..3
    const int col  = blockIdx.x * 4 + wave;      // 0..1535
    const int n = col / 6;
    const int d = col - n * 6;

    float x[4];
#pragma unroll
    for (int j = 0; j < 4; ++j)
        x[j] = fsl[(j * 64 + lane) * NCOLS + col];

    // wave max
    float mx = fmaxf(fmaxf(x[0], x[1]), fmaxf(x[2], x[3]));
#pragma unroll
    for (int off = 32; off > 0; off >>= 1)
        mx = fmaxf(mx, __shfl_xor(mx, off));

    float lo = mx - 1.0f, hi = mx;
    for (int it = 0; it < 24; ++it) {
        const float mid = 0.5f * (lo + hi);
        float s = fmaxf(x[0] - mid, 0.0f) + fmaxf(x[1] - mid, 0.0f)
                + fmaxf(x[2] - mid, 0.0f) + fmaxf(x[3] - mid, 0.0f);
#pragma unroll
        for (int off = 32; off > 0; off >>= 1)
            s += __shfl_xor(s, off);
        if (s > 1.0f) lo = mid; else hi = mid;   // uniform across wave
    }
    const float tau = 0.5f * (lo + hi);

    _Float16* dst = selT + (n * 8 + d) * KDIM;
#pragma unroll
    for (int j = 0; j < 4; ++j)
        dst[j * 64 + lane] = (_Float16)fmaxf(x[j] - tau, 0.0f);
}

// ---------------------------------------------------------------------------
// Kernel B: fp16 MFMA GEMM (fv = inputs @ selectors, padded N=2048) fused
// with sparsemoid -> leaf-weight DP -> response contraction.
// Block: 256 threads = 4 waves (2x2), tile M=128 batch x N=64 padded cols
// (= 8 trees). mfma_f32_16x16x32_f16; K=256 in 8 steps. C tiles round-trip
// through LDS (stride 68: bank-balanced) to regroup (row, tree) per thread.
// ---------------------------------------------------------------------------
#define BM 128
#define BN 64
#define BK 32
#define FVS 68   // fv LDS stride: 68 % 32 == 4 -> balanced banks for both
                 // the col-strided C-writes and the row-wise epilogue reads

__global__ __launch_bounds__(256) void odt_mfma_kernel(
    const float* __restrict__ inputs,   // [2048][256] fp32
    const _Float16* __restrict__ selT,  // [2048][256] fp16 col-major
    const float* __restrict__ thr,      // [256][6]
    const float* __restrict__ logt,     // [256][6]
    const float* __restrict__ resp,     // [256][2][64]
    float* __restrict__ out)            // [2048][512]
{
    __shared__ _Float16 Asm[BM][BK];          // 8 KB
    __shared__ _Float16 Bsm[BN][BK];          // 4 KB
    __shared__ float    fvS[BM][FVS];         // 34.8 KB
    __shared__ float    respS[8 * TREE_DIM * NLEAF]; // 4 KB

    const int tid = threadIdx.x;
    const int b0 = blockIdx.x * BM;
    const int treeBase = blockIdx.y * 8;
    const int colBase  = blockIdx.y * BN;     // padded-col units

    // Stage response tile (8 trees x 128 floats = 256 float4).
    ((float4*)respS)[tid] = ((const float4*)(resp + treeBase * TREE_DIM * NLEAF))[tid];

    const int lane = tid & 63;
    const int w    = tid >> 6;
    const int wm   = w >> 1, wn = w & 1;
    const int l16  = lane & 15, quad = lane >> 4;

    floatx4 acc[4][2];
#pragma unroll
    for (int mt = 0; mt < 4; ++mt)
#pragma unroll
        for (int nt = 0; nt < 2; ++nt)
            acc[mt][nt] = (floatx4){0.f, 0.f, 0.f, 0.f};

    // Staging thread roles (constant across K-steps)
    const int arow = tid >> 1, ach = tid & 1;          // A: 128 rows x 2 half-rows
    const int bcol = tid >> 2, bkc = tid & 3;          // B: 64 cols x 4 k-chunks

    for (int k0 = 0; k0 < KDIM; k0 += BK) {
        __syncthreads();
        // A: inputs[b0+arow][k0 + ach*16 .. +15] fp32 -> fp16
        {
            const float4* g = (const float4*)(inputs + (b0 + arow) * KDIM + k0 + ach * 16);
            const float4 v0 = g[0], v1 = g[1], v2 = g[2], v3 = g[3];
            half8 h0, h1;
            h0[0] = (_Float16)v0.x; h0[1] = (_Float16)v0.y; h0[2] = (_Float16)v0.z; h0[3] = (_Float16)v0.w;
            h0[4] = (_Float16)v1.x; h0[5] = (_Float16)v1.y; h0[6] = (_Float16)v1.z; h0[7] = (_Float16)v1.w;
            h1[0] = (_Float16)v2.x; h1[1] = (_Float16)v2.y; h1[2] = (_Float16)v2.z; h1[3] = (_Float16)v2.w;
            h1[4] = (_Float16)v3.x; h1[5] = (_Float16)v3.y; h1[6] = (_Float16)v3.z; h1[7] = (_Float16)v3.w;
            *(half8*)&Asm[arow][ach * 16]     = h0;
            *(half8*)&Asm[arow][ach * 16 + 8] = h1;
        }
        // B: selT[colBase+bcol][k0 + bkc*8 .. +7] — already fragment-ordered
        {
            const half8 v = *(const half8*)(selT + (colBase + bcol) * KDIM + k0 + bkc * 8);
            *(half8*)&Bsm[bcol][bkc * 8] = v;
        }
        __syncthreads();

        half8 bfr0 = *(half8*)&Bsm[wn * 32 + l16][quad * 8];
        half8 bfr1 = *(half8*)&Bsm[wn * 32 + 16 + l16][quad * 8];
#pragma unroll
        for (int mt = 0; mt < 4; ++mt) {
            half8 afr = *(half8*)&Asm[wm * 64 + mt * 16 + l16][quad * 8];
            acc[mt][0] = __builtin_amdgcn_mfma_f32_16x16x32_f16(afr, bfr0, acc[mt][0], 0, 0, 0);
            acc[mt][1] = __builtin_amdgcn_mfma_f32_16x16x32_f16(afr, bfr1, acc[mt][1], 0, 0, 0);
        }
    }

    // C/D layout (m89-verified, dtype-independent): col = lane&15, row = quad*4 + reg.
#pragma unroll
    for (int mt = 0; mt < 4; ++mt)
#pragma unroll
        for (int nt = 0; nt < 2; ++nt)
#pragma unroll
            for (int r = 0; r < 4; ++r)
                fvS[wm * 64 + mt * 16 + quad * 4 + r][wn * 32 + nt * 16 + l16] = acc[mt][nt][r];
    __syncthreads();

    // Epilogue: 1024 (row, tree) pairs, 4 per thread. For a given (wave, p)
    // the tree index is wave-uniform -> thr/logt/resp reads are broadcasts.
#pragma unroll
    for (int p = 0; p < 4; ++p) {
        const int idx = tid + 256 * p;
        const int row = idx & 127;
        const int tl  = idx >> 7;           // tree 0..7 in block
        const int n   = treeBase + tl;
        const float* f = &fvS[row][tl * 8];

        float sd[DEPTH];
#pragma unroll
        for (int d = 0; d < DEPTH; ++d) {
            const float tlg = (f[d] - thr[n * DEPTH + d]) * __expf(-logt[n * DEPTH + d]);
            sd[d] = fminf(fmaxf(0.5f + 0.5f * tlg, 0.0f), 1.0f);
        }
        // Leaf weights via doubling DP (bit d of leaf == 1 -> factor (1-s)).
        float wv[NLEAF];
        wv[0] = 1.0f;
#pragma unroll
        for (int d = 0; d < DEPTH; ++d) {
            const int sz = 1 << d;
#pragma unroll
            for (int c2 = 0; c2 < NLEAF / 2; ++c2) {
                if (c2 < sz) {
                    const float t = wv[c2];
                    wv[c2]      = t * sd[d];
                    wv[c2 + sz] = t * (1.0f - sd[d]);
                }
            }
        }
        const float* r0 = &respS[tl * TREE_DIM * NLEAF];
        float o0 = 0.0f, o1 = 0.0f;
#pragma unroll
        for (int c2 = 0; c2 < NLEAF; ++c2) {
            o0 = fmaf(wv[c2], r0[c2], o0);
            o1 = fmaf(wv[c2], r0[NLEAF + c2], o1);
        }
        float2 o = {o0, o1};
        *(float2*)(out + (b0 + row) * (NUM_TREES * TREE_DIM) + n * TREE_DIM) = o;
    }
}

// ---------------------------------------------------------------------------
extern "C" void kernel_launch(void* const* d_in, const int* in_sizes, int n_in,
                              void* d_out, int out_size, void* d_ws, size_t ws_size,
                              hipStream_t stream) {
    const float* inputs = (const float*)d_in[0];  // [2048][256]
    const float* fsl    = (const float*)d_in[1];  // [256][256][6]
    const float* thr    = (const float*)d_in[2];  // [256][6]
    const float* logt   = (const float*)d_in[3];  // [256][6]
    const float* resp   = (const float*)d_in[4];  // [256][2][64]
    float* out = (float*)d_out;                   // [2048][512]
    _Float16* selT = (_Float16*)d_ws;             // [2048][256] fp16 = 1 MB

    hipLaunchKernelGGL(sparsemax_bisect, dim3(NCOLS / 4), dim3(256), 0, stream, fsl, selT);
    hipLaunchKernelGGL(odt_mfma_kernel, dim3(BATCH / BM, (NUM_TREES * 8) / BN), dim3(256),
                       0, stream, inputs, selT, thr, logt, resp, out);
}